// Round 10
// baseline (387.815 us; speedup 1.0000x reference)
//
#include <hip/hip_runtime.h>
#include <hip/hip_bf16.h>

// RobertaSelfAttention, B=8,S=1024,HID=1024,H=16,D=64, relative_key_query,
// source bug v = key-projection. Output f32 [B,S,HID].

typedef float  f32x4 __attribute__((ext_vector_type(4)));
typedef short  s16x8 __attribute__((ext_vector_type(8)));
typedef unsigned short u16x4 __attribute__((ext_vector_type(4)));
typedef unsigned int   u32x4 __attribute__((ext_vector_type(4)));

#define MFMA16(a,b,c) __builtin_amdgcn_mfma_f32_16x16x32_bf16((a),(b),(c),0,0,0)

static __device__ __forceinline__ unsigned short f2b(float x){
    unsigned int u = __float_as_uint(x);
    unsigned int r = (u + 0x7fffu + ((u >> 16) & 1u)) >> 16;
    return (unsigned short)r;
}
static __device__ __forceinline__ float b2f(unsigned short b){
    return __uint_as_float(((unsigned int)b) << 16);
}
// pack two floats -> bf16x2 in one u32 (lo = a, hi = b), RNE
static __device__ __forceinline__ unsigned int cvtpk(float a, float b){
#if defined(__has_builtin) && __has_builtin(__builtin_amdgcn_cvt_pk_bf16_f32)
    typedef __bf16 bf16x2_t __attribute__((ext_vector_type(2)));
    bf16x2_t v = __builtin_amdgcn_cvt_pk_bf16_f32(a, b);
    unsigned int u; __builtin_memcpy(&u, &v, 4); return u;
#else
    return (unsigned int)f2b(a) | ((unsigned int)f2b(b) << 16);
#endif
}
static __device__ __forceinline__ void gl_lds16(const unsigned short* g, unsigned short* l){
    __builtin_amdgcn_global_load_lds(
        (const __attribute__((address_space(1))) unsigned int*)g,
        (__attribute__((address_space(3))) unsigned int*)l, 16, 0, 0);
}

// ---------------- prep_all: table + A hi/lo + W transpose fused (one launch) -----
// (validated R8: -14 us vs three separate launches)
__global__ __launch_bounds__(256)
void prep_all(const float* __restrict__ Tt, unsigned short* __restrict__ Tb,
              const float* __restrict__ Hs,
              unsigned short* __restrict__ Ahi, unsigned short* __restrict__ Alo,
              const float* __restrict__ Wq, const float* __restrict__ Wk,
              unsigned short* __restrict__ WqThi, unsigned short* __restrict__ WqTlo,
              unsigned short* __restrict__ WkThi, unsigned short* __restrict__ WkTlo){
    __shared__ unsigned short LH[64][72];
    __shared__ unsigned short LL[64][72];
    const int bid = blockIdx.x;
    const int t = threadIdx.x;

    if (bid < 512) {                               // ---- dist_table f32 -> bf16
        int i = bid * 256 + t;                     // 0 .. 131071
        if (i < 2047 * 64)      Tb[i] = f2b(Tt[i]);
        else if (i < 2048 * 64) Tb[i] = 0;
        return;
    }
    if (bid < 4608) {                              // ---- Hs -> Ahi/Alo (hi/lo split)
        int i = ((bid - 512) * 256 + t) * 8;
        float v[8];
        *(f32x4*)&v[0] = *(const f32x4*)(Hs + i);
        *(f32x4*)&v[4] = *(const f32x4*)(Hs + i + 4);
        unsigned short h8[8] __attribute__((aligned(16)));
        unsigned short l8[8] __attribute__((aligned(16)));
#pragma unroll
        for (int j = 0; j < 8; j++) {
            unsigned short h = f2b(v[j]);
            h8[j] = h;
            l8[j] = f2b(v[j] - b2f(h));
        }
        *(s16x8*)&Ahi[i] = *(s16x8*)h8;
        *(s16x8*)&Alo[i] = *(s16x8*)l8;
        return;
    }
    // ---- W [k][n] f32 -> WT_hi/lo [n][k] bf16 (LDS transpose)
    const int bx = bid - 4608;
    const float* W = (bx & 1) ? Wk : Wq;
    unsigned short* Thi = (bx & 1) ? WkThi : WqThi;
    unsigned short* Tlo = (bx & 1) ? WkTlo : WqTlo;
    const int tile = bx >> 1;                     // 0..255
    const int k0 = (tile >> 4) * 64, n0 = (tile & 15) * 64;
    const int r = t >> 3, c8 = (t & 7) * 8;
#pragma unroll
    for (int half = 0; half < 2; half++) {
        int rr = r + half * 32;
        const float* p = W + (size_t)(k0 + rr) * 1024 + n0 + c8;
        float v[8];
        *(f32x4*)&v[0] = *(const f32x4*)p;
        *(f32x4*)&v[4] = *(const f32x4*)(p + 4);
#pragma unroll
        for (int j = 0; j < 8; j++) {
            unsigned short h = f2b(v[j]);
            LH[rr][c8 + j] = h;
            LL[rr][c8 + j] = f2b(v[j] - b2f(h));
        }
    }
    __syncthreads();
    const int n = t >> 2, kg = (t & 3) * 16;
    unsigned short oh[16] __attribute__((aligned(16)));
    unsigned short ol[16] __attribute__((aligned(16)));
#pragma unroll
    for (int j = 0; j < 16; j++) { oh[j] = LH[kg + j][n]; ol[j] = LL[kg + j][n]; }
    unsigned short* dh = Thi + (size_t)(n0 + n) * 1024 + k0 + kg;
    unsigned short* dl = Tlo + (size_t)(n0 + n) * 1024 + k0 + kg;
    *(s16x8*)dh       = *(s16x8*)&oh[0];
    *(s16x8*)(dh + 8) = *(s16x8*)&oh[8];
    *(s16x8*)dl       = *(s16x8*)&ol[0];
    *(s16x8*)(dl + 8) = *(s16x8*)&ol[8];
}

// ---------------- projection GEMM v5: XCD swizzle + double-buffered K-loop --------
// (best-so-far non-attn configuration; 128^2/2-phase plateau ~625 TF)
__global__ __launch_bounds__(256, 2)
void proj_gemm(const unsigned short* __restrict__ Ahi, const unsigned short* __restrict__ Alo,
               const unsigned short* __restrict__ WqThi, const unsigned short* __restrict__ WqTlo,
               const unsigned short* __restrict__ WkThi, const unsigned short* __restrict__ WkTlo,
               const float* __restrict__ bq, const float* __restrict__ bk,
               unsigned short* __restrict__ qbf, unsigned short* __restrict__ kbf,
               unsigned short* __restrict__ kTbf)
{
    __shared__ __attribute__((aligned(16))) unsigned short SL[32768];   // 2 x 16384

    const int t = threadIdx.x, lane = t & 63, w = t >> 6;    // w in [0,4)
    const int q4 = lane >> 4, l15 = lane & 15;
    const int wm = w >> 1, wn = w & 1;
    const int bid = blockIdx.x;
    const int lid = (bid & 7) * 128 + (bid >> 3);            // XCD-chunked (bijective, 1024=8*128)
    const int ntile = lid & 15, mtile = lid >> 4;
    const int m0 = mtile * 128, cn0 = (ntile & 7) * 128;
    const unsigned short* Bh = (ntile < 8) ? WqThi : WkThi;
    const unsigned short* Bl = (ntile < 8) ? WqTlo : WkTlo;

    f32x4 acc[4][4];
#pragma unroll
    for (int i = 0; i < 4; i++)
#pragma unroll
        for (int j = 0; j < 4; j++) acc[i][j] = (f32x4){0.f, 0.f, 0.f, 0.f};

    const int lr = lane >> 2, lc = (lane & 3) * 8;

    // wave-private staging stream base (seg>>3 == w exactly)
    const unsigned short* gsb;
    if      (w == 0) gsb = Ahi + (size_t)m0 * 1024;
    else if (w == 1) gsb = Alo + (size_t)m0 * 1024;
    else if (w == 2) gsb = Bh  + (size_t)cn0 * 1024;
    else             gsb = Bl  + (size_t)cn0 * 1024;

    // prologue: stage K-step 0 into buffer 0
#pragma unroll
    for (int i = 0; i < 8; i++) {
        const unsigned short* g = gsb + (size_t)(i * 16 + lr) * 1024 + lc;
        gl_lds16(g, &SL[(w * 8 + i) * 512]);
    }
    __syncthreads();                                  // vmcnt(0) drained by compiler

    int cur = 0;
    for (int kk0 = 0; kk0 < 1024; kk0 += 32) {
        if (kk0 < 992) {
            unsigned short* dst = &SL[(cur ^ 1) << 14];
#pragma unroll
            for (int i = 0; i < 8; i++) {
                const unsigned short* g = gsb + (size_t)(i * 16 + lr) * 1024 + (kk0 + 32) + lc;
                gl_lds16(g, &dst[(w * 8 + i) * 512]);
            }
        }

        const unsigned short* B0 = &SL[cur << 14];
        s16x8 ah[4], al[4];
#pragma unroll
        for (int sm = 0; sm < 4; sm++) {
            int r = wm * 64 + sm * 16 + l15;
            ah[sm] = *(const s16x8*)&B0[r * 32 + q4 * 8];
            al[sm] = *(const s16x8*)&B0[4096 + r * 32 + q4 * 8];
        }
#pragma unroll
        for (int sn = 0; sn < 4; sn++) {
            int r = wn * 64 + sn * 16 + l15;
            const s16x8 bh8 = *(const s16x8*)&B0[8192 + r * 32 + q4 * 8];
            const s16x8 bl8 = *(const s16x8*)&B0[12288 + r * 32 + q4 * 8];
#pragma unroll
            for (int sm = 0; sm < 4; sm++) {
                f32x4 a = acc[sm][sn];
                a = MFMA16(ah[sm], bh8, a);
                a = MFMA16(ah[sm], bl8, a);
                a = MFMA16(al[sm], bh8, a);
                acc[sm][sn] = a;
            }
        }
        __syncthreads();        // drains vmcnt(0): next buffer ready, this one free
        cur ^= 1;
    }

#pragma unroll
    for (int sm = 0; sm < 4; sm++) {
#pragma unroll
        for (int sn = 0; sn < 4; sn++) {
            const int coln = ntile * 128 + wn * 64 + sn * 16 + l15;
            const float bias = (ntile < 8) ? bq[coln] : bk[coln - 1024];
            const int mbase = m0 + wm * 64 + sm * 16 + q4 * 4;
            const int bb = mbase >> 10, ss0 = mbase & 1023;
            unsigned short vb[4];
#pragma unroll
            for (int reg = 0; reg < 4; reg++) vb[reg] = f2b(acc[sm][sn][reg] + bias);
            if (ntile < 8) {
                const int hh = coln >> 6, d = coln & 63;
#pragma unroll
                for (int reg = 0; reg < 4; reg++)
                    qbf[(((size_t)(bb * 16 + hh) * 1024) + ss0 + reg) * 64 + d] = vb[reg];
            } else {
                const int ck = coln - 1024;
                const int hh = ck >> 6, d = ck & 63;
#pragma unroll
                for (int reg = 0; reg < 4; reg++)
                    kbf[(((size_t)(bb * 16 + hh) * 1024) + ss0 + reg) * 64 + d] = vb[reg];
                u16x4 pk = { vb[0], vb[1], vb[2], vb[3] };
                *(u16x4*)&kTbf[(((size_t)(bb * 16 + hh) * 64) + d) * 1024 + ss0] = pk;
            }
        }
    }
}

// ---------------- fused attention v12 = v4 byte-exact ------------------------------
// R9's invariant-hoist/psum-split cost +3.5 us (added cross-loop liveness).
// Reverted to the proven 204-us body. Measured bans: s_setprio (spill), gq carry
// (dep chain), exp2f (conformant OCML path), hoist tables (liveness).
__global__ __launch_bounds__(512, 4)
void attn(const unsigned short* __restrict__ qbf, const unsigned short* __restrict__ kbf,
          const unsigned short* __restrict__ kTbf, const unsigned short* __restrict__ Tbf,
          float* __restrict__ out)
{
    __shared__ __attribute__((aligned(16))) unsigned char LDSRAW[59392];
    unsigned short* Klds = (unsigned short*)LDSRAW;              // 64x64 swizzled (8 KB)
    unsigned short* Tlds = (unsigned short*)(LDSRAW + 8192);     // 192-row circular (24 KB)
    unsigned int*   GqS  = (unsigned int*)(LDSRAW + 32768);      // 8w x 16x20 u32 (10 KB)
    unsigned short* Pw   = (unsigned short*)(LDSRAW + 43008);    // 8w x 16x64 bf16 (16 KB)
    float*          Ep   = (float*)LDSRAW;                       // epilogue overlay

    const int t = threadIdx.x;
    const int lane = t & 63, w = t >> 6;
    const int q4 = lane >> 4, l15 = lane & 15;
    const int swz8 = (l15 & 7) * 8;
    const int bh = blockIdx.x & 127;
    const int lb = (blockIdx.x >> 7) * 128;
    const int l0w = lb + w * 16;

    const unsigned short* qb = qbf + (size_t)bh * 65536;
    const unsigned short* kb = kbf + (size_t)bh * 65536;
    const unsigned short* kT = kTbf + (size_t)bh * 65536;

    const s16x8 qf0 = *(const s16x8*)(qb + (l0w + l15) * 64 + q4 * 8);
    const s16x8 qf1 = *(const s16x8*)(qb + (l0w + l15) * 64 + 32 + q4 * 8);

    // DMA lane map: lane j -> seg row j>>3, global col-group (j&7)^(j>>3) (swizzle at source)
    const int dj_r = lane >> 3;
    const int dj_c = ((lane & 7) ^ dj_r) * 8;

    // ---- prestage chunk 0: 24 T segs (phys [0,192) = global [lb+960, lb+1152)) + 8 K segs
#pragma unroll
    for (int i = 0; i < 4; i++) {
        const int seg = w * 4 + i;
        if (seg < 24) {
            const unsigned short* g = Tbf + (size_t)(lb + 960 + seg * 8 + dj_r) * 64 + dj_c;
            gl_lds16(g, Tlds + seg * 512);
        } else {
            const int s = seg - 24;
            const unsigned short* g = kb + (size_t)(s * 8 + dj_r) * 64 + dj_c;
            gl_lds16(g, Klds + s * 512);
        }
    }
    __syncthreads();

    f32x4 pacc[4];
#pragma unroll
    for (int n = 0; n < 4; n++) pacc[n] = (f32x4){0.f, 0.f, 0.f, 0.f};
    float psum = 0.f;

    unsigned int*   GqW = GqS + w * 320;      // 16 rows (band n) x stride 20, cols l
    unsigned short* PwW = Pw + w * 1024;

    // initial carried tfB: chunk0/rs0 band upper half = phys rows [64+w*16, +16)
    const int pB0 = 64 + w * 16 + l15;
    s16x8 tb0 = *(const s16x8*)&Tlds[pB0 * 64 + ((q4 * 8) ^ swz8)];
    s16x8 tb1 = *(const s16x8*)&Tlds[pB0 * 64 + ((32 + q4 * 8) ^ swz8)];

    int r0 = 0;
    for (int c = 0; c < 16; c++) {
        // hoist PV V^T loads (global, L2-resident)
        s16x8 vf[4][2];
#pragma unroll
        for (int n = 0; n < 4; n++) {
            const unsigned short* vp = kT + (size_t)(n * 16 + l15) * 1024 + r0;
            vf[n][0] = *(const s16x8*)(vp + q4 * 8);
            vf[n][1] = *(const s16x8*)(vp + 32 + q4 * 8);
        }

        const int base = 1008 - 64 * c + w * 16;
#pragma unroll
        for (int rs = 0; rs < 4; rs++) {
            const int krow = rs * 16 + l15;
            const s16x8 kf0 = *(const s16x8*)&Klds[krow * 64 + ((q4 * 8) ^ swz8)];
            const s16x8 kf1 = *(const s16x8*)&Klds[krow * 64 + ((32 + q4 * 8) ^ swz8)];

            const int p0 = (base - rs * 16) % 192;          // wave-uniform
            int pa = p0 + l15; if (pa >= 192) pa -= 192;
            const s16x8 ta0 = *(const s16x8*)&Tlds[pa * 64 + ((q4 * 8) ^ swz8)];
            const s16x8 ta1 = *(const s16x8*)&Tlds[pa * 64 + ((32 + q4 * 8) ^ swz8)];

            f32x4 s = (f32x4){0.f, 0.f, 0.f, 0.f};
            s = MFMA16(kf0, qf0, s);
            s = MFMA16(kf1, qf1, s);

            f32x4 gq0 = (f32x4){0.f,0.f,0.f,0.f}, gq1 = (f32x4){0.f,0.f,0.f,0.f};
            f32x4 hk0 = (f32x4){0.f,0.f,0.f,0.f}, hk1 = (f32x4){0.f,0.f,0.f,0.f};
            gq0 = MFMA16(qf0, ta0, gq0); gq0 = MFMA16(qf1, ta1, gq0);   // band n<16
            gq1 = MFMA16(qf0, tb0, gq1); gq1 = MFMA16(qf1, tb1, gq1);   // band n>=16
            hk0 = MFMA16(kf0, ta0, hk0); hk0 = MFMA16(kf1, ta1, hk0);
            hk1 = MFMA16(kf0, tb0, hk1); hk1 = MFMA16(kf1, tb1, hk1);

            // Gq -> G[n=l15][l = q4*4+reg] packed (lo = n<16, hi = n>=16), 1 b128
            u32x4 gpk;
#pragma unroll
            for (int reg = 0; reg < 4; reg++) gpk[reg] = cvtpk(gq0[reg], gq1[reg]);
            *(u32x4*)&GqW[l15 * 20 + q4 * 4] = gpk;

            // per-reg: relk via packed bpermute from same-reg lanes, relq from G
            const int n4b = l15 - q4 * 4 + 15;
            float pr[4];
#pragma unroll
            for (int reg = 0; reg < 4; reg++) {
                const int n4 = n4b - reg;                  // 0..30
                const int srclane = (n4 & 15) | (lane & 48);
                const unsigned int hpk = cvtpk(hk0[reg], hk1[reg]);
                const unsigned int gsh = (unsigned int)__shfl((int)hpk, srclane);
                const unsigned int rkb = (n4 < 16) ? (gsh << 16) : (gsh & 0xffff0000u);
                const unsigned int gq  = GqW[(n4 & 15) * 20 + l15];
                const unsigned int rqb = (n4 < 16) ? (gq << 16) : (gq & 0xffff0000u);
                float sc = (s[reg] + __uint_as_float(rqb) + __uint_as_float(rkb)) * 0.125f - 4.0f;
                float p = __expf(sc);
                psum += p;
                pr[reg] = p;
            }
            unsigned int u0 = cvtpk(pr[0], pr[1]);
            unsigned int u1 = cvtpk(pr[2], pr[3]);
            unsigned long long pk2 = (unsigned long long)u0 | ((unsigned long long)u1 << 32);
            *(unsigned long long*)&PwW[l15 * 64 + ((rs * 16 + q4 * 4) ^ swz8)] = pk2;

            tb0 = ta0; tb1 = ta1;                          // carry band half
        }

        // PV: ctx^T[d][l] += V^T[d][r] * P^T[r][l]
        const s16x8 pf0 = *(const s16x8*)&PwW[l15 * 64 + ((q4 * 8) ^ swz8)];
        const s16x8 pf1 = *(const s16x8*)&PwW[l15 * 64 + ((32 + q4 * 8) ^ swz8)];
#pragma unroll
        for (int n = 0; n < 4; n++) {
            pacc[n] = MFMA16(vf[n][0], pf0, pacc[n]);
            pacc[n] = MFMA16(vf[n][1], pf1, pacc[n]);
        }

        if (c < 15) {
            __syncthreads();                               // chunk-c LDS reads done
            const int cn = c + 1;
            {   // K chunk cn, seg w
                const unsigned short* g = kb + (size_t)(cn * 64 + w * 8 + dj_r) * 64 + dj_c;
                gl_lds16(g, Klds + w * 512);
            }
            {   // T new 64 rows, seg w; phys base = (-64*cn) mod 192
                const int pnew = (1152 - 64 * cn) % 192;
                const unsigned short* g = Tbf + (size_t)(lb + 960 - 64 * cn + w * 8 + dj_r) * 64 + dj_c;
                gl_lds16(g, Tlds + pnew * 64 + w * 512);
            }
            __syncthreads();                               // DMA drained (vmcnt 0)
        }
        r0 += 64;
    }

    // softmax denominators: column l = l15 summed across q4 groups
    psum += __shfl_xor(psum, 16);
    psum += __shfl_xor(psum, 32);
    const float inv = 1.0f / psum;

    __syncthreads();                                       // done with K/T/Gq LDS
    float* EpW = Ep + w * 1088;                            // 16 x 68 f32
#pragma unroll
    for (int n = 0; n < 4; n++) {
        f32x4 v = pacc[n];
        v[0] *= inv; v[1] *= inv; v[2] *= inv; v[3] *= inv;
        *(f32x4*)&EpW[l15 * 68 + n * 16 + q4 * 4] = v;
    }
    const int b0 = bh >> 4, hh = bh & 15;
    const int li = lane >> 2, gg = lane & 3;
#pragma unroll
    for (int cc = 0; cc < 4; cc++) {
        f32x4 v = *(const f32x4*)&EpW[li * 68 + gg * 16 + cc * 4];
        *(f32x4*)&out[((size_t)(b0 * 1024 + l0w + li) * 1024) + hh * 64 + gg * 16 + cc * 4] = v;
    }
}

// ---------------- launch ----------------------------------------------------------
extern "C" void kernel_launch(void* const* d_in, const int* in_sizes, int n_in,
                              void* d_out, int out_size, void* d_ws, size_t ws_size,
                              hipStream_t stream) {
    (void)in_sizes; (void)n_in; (void)out_size; (void)ws_size;
    const float* Hs = (const float*)d_in[0];
    const float* Wq = (const float*)d_in[1];
    const float* bq = (const float*)d_in[2];
    const float* Wk = (const float*)d_in[3];
    const float* bk = (const float*)d_in[4];
    // d_in[5], d_in[6] (Wv, bv) unused: reference's v uses the k projection.
    const float* Tt = (const float*)d_in[7];
    float* out = (float*)d_out;

    unsigned short* qbf   = (unsigned short*)d_ws;
    unsigned short* kbf   = qbf  + (size_t)8 * 1024 * 1024;
    unsigned short* kTbf  = kbf  + (size_t)8 * 1024 * 1024;
    unsigned short* Tbf   = kTbf + (size_t)8 * 1024 * 1024;
    unsigned short* Ahi   = Tbf  + (size_t)2048 * 64;
    unsigned short* Alo   = Ahi  + (size_t)8 * 1024 * 1024;
    unsigned short* WqThi = Alo  + (size_t)8 * 1024 * 1024;
    unsigned short* WqTlo = WqThi + (size_t)1024 * 1024;
    unsigned short* WkThi = WqTlo + (size_t)1024 * 1024;
    unsigned short* WkTlo = WkThi + (size_t)1024 * 1024;

    hipLaunchKernelGGL(prep_all, dim3(5120), dim3(256), 0, stream,
                       Tt, Tbf, Hs, Ahi, Alo, Wq, Wk, WqThi, WqTlo, WkThi, WkTlo);
    hipLaunchKernelGGL(proj_gemm, dim3(1024), dim3(256), 0, stream,
                       Ahi, Alo, WqThi, WqTlo, WkThi, WkTlo, bq, bk, qbf, kbf, kTbf);
    hipLaunchKernelGGL(attn, dim3(1024), dim3(512), 0, stream,
                       qbf, kbf, kTbf, Tbf, out);
}

// Round 11
// 359.608 us; speedup vs baseline: 1.0784x; 1.0784x over previous
//
#include <hip/hip_runtime.h>
#include <hip/hip_bf16.h>

// RobertaSelfAttention, B=8,S=1024,HID=1024,H=16,D=64, relative_key_query,
// source bug v = key-projection. Output f32 [B,S,HID].

typedef float  f32x4 __attribute__((ext_vector_type(4)));
typedef short  s16x8 __attribute__((ext_vector_type(8)));
typedef unsigned short u16x4 __attribute__((ext_vector_type(4)));
typedef unsigned int   u32x4 __attribute__((ext_vector_type(4)));

#define MFMA16(a,b,c) __builtin_amdgcn_mfma_f32_16x16x32_bf16((a),(b),(c),0,0,0)

static __device__ __forceinline__ unsigned short f2b(float x){
    unsigned int u = __float_as_uint(x);
    unsigned int r = (u + 0x7fffu + ((u >> 16) & 1u)) >> 16;
    return (unsigned short)r;
}
static __device__ __forceinline__ float b2f(unsigned short b){
    return __uint_as_float(((unsigned int)b) << 16);
}
// pack two floats -> bf16x2 in one u32 (lo = a, hi = b), RNE
static __device__ __forceinline__ unsigned int cvtpk(float a, float b){
#if defined(__has_builtin) && __has_builtin(__builtin_amdgcn_cvt_pk_bf16_f32)
    typedef __bf16 bf16x2_t __attribute__((ext_vector_type(2)));
    bf16x2_t v = __builtin_amdgcn_cvt_pk_bf16_f32(a, b);
    unsigned int u; __builtin_memcpy(&u, &v, 4); return u;
#else
    return (unsigned int)f2b(a) | ((unsigned int)f2b(b) << 16);
#endif
}
// raw v_exp_f32 (2^x) — bare instruction, NOT the conformant OCML exp2f
static __device__ __forceinline__ float exp2raw(float x){
#if defined(__has_builtin) && __has_builtin(__builtin_amdgcn_exp2f)
    return __builtin_amdgcn_exp2f(x);
#else
    return __expf(x * 0.6931471805599453f);
#endif
}
static __device__ __forceinline__ void gl_lds16(const unsigned short* g, unsigned short* l){
    __builtin_amdgcn_global_load_lds(
        (const __attribute__((address_space(1))) unsigned int*)g,
        (__attribute__((address_space(3))) unsigned int*)l, 16, 0, 0);
}

// ---------------- prep_all: table + A hi/lo + W transpose fused (one launch) -----
// (validated R8: -14 us vs three separate launches)
__global__ __launch_bounds__(256)
void prep_all(const float* __restrict__ Tt, unsigned short* __restrict__ Tb,
              const float* __restrict__ Hs,
              unsigned short* __restrict__ Ahi, unsigned short* __restrict__ Alo,
              const float* __restrict__ Wq, const float* __restrict__ Wk,
              unsigned short* __restrict__ WqThi, unsigned short* __restrict__ WqTlo,
              unsigned short* __restrict__ WkThi, unsigned short* __restrict__ WkTlo){
    __shared__ unsigned short LH[64][72];
    __shared__ unsigned short LL[64][72];
    const int bid = blockIdx.x;
    const int t = threadIdx.x;

    if (bid < 512) {                               // ---- dist_table f32 -> bf16
        int i = bid * 256 + t;                     // 0 .. 131071
        if (i < 2047 * 64)      Tb[i] = f2b(Tt[i]);
        else if (i < 2048 * 64) Tb[i] = 0;
        return;
    }
    if (bid < 4608) {                              // ---- Hs -> Ahi/Alo (hi/lo split)
        int i = ((bid - 512) * 256 + t) * 8;
        float v[8];
        *(f32x4*)&v[0] = *(const f32x4*)(Hs + i);
        *(f32x4*)&v[4] = *(const f32x4*)(Hs + i + 4);
        unsigned short h8[8] __attribute__((aligned(16)));
        unsigned short l8[8] __attribute__((aligned(16)));
#pragma unroll
        for (int j = 0; j < 8; j++) {
            unsigned short h = f2b(v[j]);
            h8[j] = h;
            l8[j] = f2b(v[j] - b2f(h));
        }
        *(s16x8*)&Ahi[i] = *(s16x8*)h8;
        *(s16x8*)&Alo[i] = *(s16x8*)l8;
        return;
    }
    // ---- W [k][n] f32 -> WT_hi/lo [n][k] bf16 (LDS transpose)
    const int bx = bid - 4608;
    const float* W = (bx & 1) ? Wk : Wq;
    unsigned short* Thi = (bx & 1) ? WkThi : WqThi;
    unsigned short* Tlo = (bx & 1) ? WkTlo : WqTlo;
    const int tile = bx >> 1;                     // 0..255
    const int k0 = (tile >> 4) * 64, n0 = (tile & 15) * 64;
    const int r = t >> 3, c8 = (t & 7) * 8;
#pragma unroll
    for (int half = 0; half < 2; half++) {
        int rr = r + half * 32;
        const float* p = W + (size_t)(k0 + rr) * 1024 + n0 + c8;
        float v[8];
        *(f32x4*)&v[0] = *(const f32x4*)p;
        *(f32x4*)&v[4] = *(const f32x4*)(p + 4);
#pragma unroll
        for (int j = 0; j < 8; j++) {
            unsigned short h = f2b(v[j]);
            LH[rr][c8 + j] = h;
            LL[rr][c8 + j] = f2b(v[j] - b2f(h));
        }
    }
    __syncthreads();
    const int n = t >> 2, kg = (t & 3) * 16;
    unsigned short oh[16] __attribute__((aligned(16)));
    unsigned short ol[16] __attribute__((aligned(16)));
#pragma unroll
    for (int j = 0; j < 16; j++) { oh[j] = LH[kg + j][n]; ol[j] = LL[kg + j][n]; }
    unsigned short* dh = Thi + (size_t)(n0 + n) * 1024 + k0 + kg;
    unsigned short* dl = Tlo + (size_t)(n0 + n) * 1024 + k0 + kg;
    *(s16x8*)dh       = *(s16x8*)&oh[0];
    *(s16x8*)(dh + 8) = *(s16x8*)&oh[8];
    *(s16x8*)dl       = *(s16x8*)&ol[0];
    *(s16x8*)(dl + 8) = *(s16x8*)&ol[8];
}

// ---------------- projection GEMM v5: XCD swizzle + double-buffered K-loop --------
// (best-so-far non-attn configuration; 128^2/2-phase plateau ~625 TF)
__global__ __launch_bounds__(256, 2)
void proj_gemm(const unsigned short* __restrict__ Ahi, const unsigned short* __restrict__ Alo,
               const unsigned short* __restrict__ WqThi, const unsigned short* __restrict__ WqTlo,
               const unsigned short* __restrict__ WkThi, const unsigned short* __restrict__ WkTlo,
               const float* __restrict__ bq, const float* __restrict__ bk,
               unsigned short* __restrict__ qbf, unsigned short* __restrict__ kbf,
               unsigned short* __restrict__ kTbf)
{
    __shared__ __attribute__((aligned(16))) unsigned short SL[32768];   // 2 x 16384

    const int t = threadIdx.x, lane = t & 63, w = t >> 6;    // w in [0,4)
    const int q4 = lane >> 4, l15 = lane & 15;
    const int wm = w >> 1, wn = w & 1;
    const int bid = blockIdx.x;
    const int lid = (bid & 7) * 128 + (bid >> 3);            // XCD-chunked (bijective, 1024=8*128)
    const int ntile = lid & 15, mtile = lid >> 4;
    const int m0 = mtile * 128, cn0 = (ntile & 7) * 128;
    const unsigned short* Bh = (ntile < 8) ? WqThi : WkThi;
    const unsigned short* Bl = (ntile < 8) ? WqTlo : WkTlo;

    f32x4 acc[4][4];
#pragma unroll
    for (int i = 0; i < 4; i++)
#pragma unroll
        for (int j = 0; j < 4; j++) acc[i][j] = (f32x4){0.f, 0.f, 0.f, 0.f};

    const int lr = lane >> 2, lc = (lane & 3) * 8;

    // wave-private staging stream base (seg>>3 == w exactly)
    const unsigned short* gsb;
    if      (w == 0) gsb = Ahi + (size_t)m0 * 1024;
    else if (w == 1) gsb = Alo + (size_t)m0 * 1024;
    else if (w == 2) gsb = Bh  + (size_t)cn0 * 1024;
    else             gsb = Bl  + (size_t)cn0 * 1024;

    // prologue: stage K-step 0 into buffer 0
#pragma unroll
    for (int i = 0; i < 8; i++) {
        const unsigned short* g = gsb + (size_t)(i * 16 + lr) * 1024 + lc;
        gl_lds16(g, &SL[(w * 8 + i) * 512]);
    }
    __syncthreads();                                  // vmcnt(0) drained by compiler

    int cur = 0;
    for (int kk0 = 0; kk0 < 1024; kk0 += 32) {
        if (kk0 < 992) {
            unsigned short* dst = &SL[(cur ^ 1) << 14];
#pragma unroll
            for (int i = 0; i < 8; i++) {
                const unsigned short* g = gsb + (size_t)(i * 16 + lr) * 1024 + (kk0 + 32) + lc;
                gl_lds16(g, &dst[(w * 8 + i) * 512]);
            }
        }

        const unsigned short* B0 = &SL[cur << 14];
        s16x8 ah[4], al[4];
#pragma unroll
        for (int sm = 0; sm < 4; sm++) {
            int r = wm * 64 + sm * 16 + l15;
            ah[sm] = *(const s16x8*)&B0[r * 32 + q4 * 8];
            al[sm] = *(const s16x8*)&B0[4096 + r * 32 + q4 * 8];
        }
#pragma unroll
        for (int sn = 0; sn < 4; sn++) {
            int r = wn * 64 + sn * 16 + l15;
            const s16x8 bh8 = *(const s16x8*)&B0[8192 + r * 32 + q4 * 8];
            const s16x8 bl8 = *(const s16x8*)&B0[12288 + r * 32 + q4 * 8];
#pragma unroll
            for (int sm = 0; sm < 4; sm++) {
                f32x4 a = acc[sm][sn];
                a = MFMA16(ah[sm], bh8, a);
                a = MFMA16(ah[sm], bl8, a);
                a = MFMA16(al[sm], bh8, a);
                acc[sm][sn] = a;
            }
        }
        __syncthreads();        // drains vmcnt(0): next buffer ready, this one free
        cur ^= 1;
    }

#pragma unroll
    for (int sm = 0; sm < 4; sm++) {
#pragma unroll
        for (int sn = 0; sn < 4; sn++) {
            const int coln = ntile * 128 + wn * 64 + sn * 16 + l15;
            const float bias = (ntile < 8) ? bq[coln] : bk[coln - 1024];
            const int mbase = m0 + wm * 64 + sm * 16 + q4 * 4;
            const int bb = mbase >> 10, ss0 = mbase & 1023;
            unsigned short vb[4];
#pragma unroll
            for (int reg = 0; reg < 4; reg++) vb[reg] = f2b(acc[sm][sn][reg] + bias);
            if (ntile < 8) {
                const int hh = coln >> 6, d = coln & 63;
#pragma unroll
                for (int reg = 0; reg < 4; reg++)
                    qbf[(((size_t)(bb * 16 + hh) * 1024) + ss0 + reg) * 64 + d] = vb[reg];
            } else {
                const int ck = coln - 1024;
                const int hh = ck >> 6, d = ck & 63;
#pragma unroll
                for (int reg = 0; reg < 4; reg++)
                    kbf[(((size_t)(bb * 16 + hh) * 1024) + ss0 + reg) * 64 + d] = vb[reg];
                u16x4 pk = { vb[0], vb[1], vb[2], vb[3] };
                *(u16x4*)&kTbf[(((size_t)(bb * 16 + hh) * 64) + d) * 1024 + ss0] = pk;
            }
        }
    }
}

// ---------------- fused attention v13 = v4 + ones-MFMA denominator + raw exp2 -----
// Two strict op-removals vs the proven v4 body (no added cross-loop liveness):
//  * psum (256 serial VALU adds + 2 shfls) -> psacc = MFMA16(ones, pf, psacc):
//    all-ones A makes every output the column-sum of B, so each lane gets
//    sum_r P[r][l15] directly. 32 extra MFMAs on the 19%-utilized matrix pipe.
//    Denominator now sums bf16-rounded p (RNE, unbiased; ~6e-5 rel perturbation).
//  * exp via raw v_exp_f32 builtin on pre-fused arg (fma + exp, saving the
//    log2e mul __expf emits). NOT the OCML exp2f (that was the R4 +16us trap).
// Bans (measured): s_setprio (spill), gq carry (dep), OCML exp2f, hoist tables.
__global__ __launch_bounds__(512, 4)
void attn(const unsigned short* __restrict__ qbf, const unsigned short* __restrict__ kbf,
          const unsigned short* __restrict__ kTbf, const unsigned short* __restrict__ Tbf,
          float* __restrict__ out)
{
    __shared__ __attribute__((aligned(16))) unsigned char LDSRAW[59392];
    unsigned short* Klds = (unsigned short*)LDSRAW;              // 64x64 swizzled (8 KB)
    unsigned short* Tlds = (unsigned short*)(LDSRAW + 8192);     // 192-row circular (24 KB)
    unsigned int*   GqS  = (unsigned int*)(LDSRAW + 32768);      // 8w x 16x20 u32 (10 KB)
    unsigned short* Pw   = (unsigned short*)(LDSRAW + 43008);    // 8w x 16x64 bf16 (16 KB)
    float*          Ep   = (float*)LDSRAW;                       // epilogue overlay

    const int t = threadIdx.x;
    const int lane = t & 63, w = t >> 6;
    const int q4 = lane >> 4, l15 = lane & 15;
    const int swz8 = (l15 & 7) * 8;
    const int bh = blockIdx.x & 127;
    const int lb = (blockIdx.x >> 7) * 128;
    const int l0w = lb + w * 16;

    const unsigned short* qb = qbf + (size_t)bh * 65536;
    const unsigned short* kb = kbf + (size_t)bh * 65536;
    const unsigned short* kT = kTbf + (size_t)bh * 65536;

    const s16x8 qf0 = *(const s16x8*)(qb + (l0w + l15) * 64 + q4 * 8);
    const s16x8 qf1 = *(const s16x8*)(qb + (l0w + l15) * 64 + 32 + q4 * 8);

    // all-ones bf16 fragment for the denominator MFMA
    const short oneb = (short)0x3F80;
    const s16x8 ones = { oneb, oneb, oneb, oneb, oneb, oneb, oneb, oneb };

    // DMA lane map: lane j -> seg row j>>3, global col-group (j&7)^(j>>3) (swizzle at source)
    const int dj_r = lane >> 3;
    const int dj_c = ((lane & 7) ^ dj_r) * 8;

    // ---- prestage chunk 0: 24 T segs (phys [0,192) = global [lb+960, lb+1152)) + 8 K segs
#pragma unroll
    for (int i = 0; i < 4; i++) {
        const int seg = w * 4 + i;
        if (seg < 24) {
            const unsigned short* g = Tbf + (size_t)(lb + 960 + seg * 8 + dj_r) * 64 + dj_c;
            gl_lds16(g, Tlds + seg * 512);
        } else {
            const int s = seg - 24;
            const unsigned short* g = kb + (size_t)(s * 8 + dj_r) * 64 + dj_c;
            gl_lds16(g, Klds + s * 512);
        }
    }
    __syncthreads();

    f32x4 pacc[4];
#pragma unroll
    for (int n = 0; n < 4; n++) pacc[n] = (f32x4){0.f, 0.f, 0.f, 0.f};
    f32x4 psacc = (f32x4){0.f, 0.f, 0.f, 0.f};

    unsigned int*   GqW = GqS + w * 320;      // 16 rows (band n) x stride 20, cols l
    unsigned short* PwW = Pw + w * 1024;

    // initial carried tfB: chunk0/rs0 band upper half = phys rows [64+w*16, +16)
    const int pB0 = 64 + w * 16 + l15;
    s16x8 tb0 = *(const s16x8*)&Tlds[pB0 * 64 + ((q4 * 8) ^ swz8)];
    s16x8 tb1 = *(const s16x8*)&Tlds[pB0 * 64 + ((32 + q4 * 8) ^ swz8)];

    int r0 = 0;
    for (int c = 0; c < 16; c++) {
        // hoist PV V^T loads (global, L2-resident)
        s16x8 vf[4][2];
#pragma unroll
        for (int n = 0; n < 4; n++) {
            const unsigned short* vp = kT + (size_t)(n * 16 + l15) * 1024 + r0;
            vf[n][0] = *(const s16x8*)(vp + q4 * 8);
            vf[n][1] = *(const s16x8*)(vp + 32 + q4 * 8);
        }

        const int base = 1008 - 64 * c + w * 16;
#pragma unroll
        for (int rs = 0; rs < 4; rs++) {
            const int krow = rs * 16 + l15;
            const s16x8 kf0 = *(const s16x8*)&Klds[krow * 64 + ((q4 * 8) ^ swz8)];
            const s16x8 kf1 = *(const s16x8*)&Klds[krow * 64 + ((32 + q4 * 8) ^ swz8)];

            const int p0 = (base - rs * 16) % 192;          // wave-uniform
            int pa = p0 + l15; if (pa >= 192) pa -= 192;
            const s16x8 ta0 = *(const s16x8*)&Tlds[pa * 64 + ((q4 * 8) ^ swz8)];
            const s16x8 ta1 = *(const s16x8*)&Tlds[pa * 64 + ((32 + q4 * 8) ^ swz8)];

            f32x4 s = (f32x4){0.f, 0.f, 0.f, 0.f};
            s = MFMA16(kf0, qf0, s);
            s = MFMA16(kf1, qf1, s);

            f32x4 gq0 = (f32x4){0.f,0.f,0.f,0.f}, gq1 = (f32x4){0.f,0.f,0.f,0.f};
            f32x4 hk0 = (f32x4){0.f,0.f,0.f,0.f}, hk1 = (f32x4){0.f,0.f,0.f,0.f};
            gq0 = MFMA16(qf0, ta0, gq0); gq0 = MFMA16(qf1, ta1, gq0);   // band n<16
            gq1 = MFMA16(qf0, tb0, gq1); gq1 = MFMA16(qf1, tb1, gq1);   // band n>=16
            hk0 = MFMA16(kf0, ta0, hk0); hk0 = MFMA16(kf1, ta1, hk0);
            hk1 = MFMA16(kf0, tb0, hk1); hk1 = MFMA16(kf1, tb1, hk1);

            // Gq -> G[n=l15][l = q4*4+reg] packed (lo = n<16, hi = n>=16), 1 b128
            u32x4 gpk;
#pragma unroll
            for (int reg = 0; reg < 4; reg++) gpk[reg] = cvtpk(gq0[reg], gq1[reg]);
            *(u32x4*)&GqW[l15 * 20 + q4 * 4] = gpk;

            // per-reg: relk via packed bpermute from same-reg lanes, relq from G
            const int n4b = l15 - q4 * 4 + 15;
            float pr[4];
#pragma unroll
            for (int reg = 0; reg < 4; reg++) {
                const int n4 = n4b - reg;                  // 0..30
                const int srclane = (n4 & 15) | (lane & 48);
                const unsigned int hpk = cvtpk(hk0[reg], hk1[reg]);
                const unsigned int gsh = (unsigned int)__shfl((int)hpk, srclane);
                const unsigned int rkb = (n4 < 16) ? (gsh << 16) : (gsh & 0xffff0000u);
                const unsigned int gq  = GqW[(n4 & 15) * 20 + l15];
                const unsigned int rqb = (n4 < 16) ? (gq << 16) : (gq & 0xffff0000u);
                // exp((x)*0.125 - 4) = 2^(x*0.125*log2e - 4*log2e), raw v_exp_f32
                const float x = s[reg] + __uint_as_float(rqb) + __uint_as_float(rkb);
                float p = exp2raw(fmaf(x, 0.18033688011112042f, -5.770780163555853f));
                pr[reg] = p;
            }
            unsigned int u0 = cvtpk(pr[0], pr[1]);
            unsigned int u1 = cvtpk(pr[2], pr[3]);
            unsigned long long pk2 = (unsigned long long)u0 | ((unsigned long long)u1 << 32);
            *(unsigned long long*)&PwW[l15 * 64 + ((rs * 16 + q4 * 4) ^ swz8)] = pk2;

            tb0 = ta0; tb1 = ta1;                          // carry band half
        }

        // PV: ctx^T[d][l] += V^T[d][r] * P^T[r][l]; denominator via ones-row MFMA
        const s16x8 pf0 = *(const s16x8*)&PwW[l15 * 64 + ((q4 * 8) ^ swz8)];
        const s16x8 pf1 = *(const s16x8*)&PwW[l15 * 64 + ((32 + q4 * 8) ^ swz8)];
#pragma unroll
        for (int n = 0; n < 4; n++) {
            pacc[n] = MFMA16(vf[n][0], pf0, pacc[n]);
            pacc[n] = MFMA16(vf[n][1], pf1, pacc[n]);
        }
        psacc = MFMA16(ones, pf0, psacc);
        psacc = MFMA16(ones, pf1, psacc);

        if (c < 15) {
            __syncthreads();                               // chunk-c LDS reads done
            const int cn = c + 1;
            {   // K chunk cn, seg w
                const unsigned short* g = kb + (size_t)(cn * 64 + w * 8 + dj_r) * 64 + dj_c;
                gl_lds16(g, Klds + w * 512);
            }
            {   // T new 64 rows, seg w; phys base = (-64*cn) mod 192
                const int pnew = (1152 - 64 * cn) % 192;
                const unsigned short* g = Tbf + (size_t)(lb + 960 - 64 * cn + w * 8 + dj_r) * 64 + dj_c;
                gl_lds16(g, Tlds + pnew * 64 + w * 512);
            }
            __syncthreads();                               // DMA drained (vmcnt 0)
        }
        r0 += 64;
    }

    // denominator: every lane's psacc[0] = sum_r P[r][l15] (ones-A replicates
    // the column sum across all rows, so no cross-lane reduction needed)
    const float inv = 1.0f / psacc[0];

    __syncthreads();                                       // done with K/T/Gq LDS
    float* EpW = Ep + w * 1088;                            // 16 x 68 f32
#pragma unroll
    for (int n = 0; n < 4; n++) {
        f32x4 v = pacc[n];
        v[0] *= inv; v[1] *= inv; v[2] *= inv; v[3] *= inv;
        *(f32x4*)&EpW[l15 * 68 + n * 16 + q4 * 4] = v;
    }
    const int b0 = bh >> 4, hh = bh & 15;
    const int li = lane >> 2, gg = lane & 3;
#pragma unroll
    for (int cc = 0; cc < 4; cc++) {
        f32x4 v = *(const f32x4*)&EpW[li * 68 + gg * 16 + cc * 4];
        *(f32x4*)&out[((size_t)(b0 * 1024 + l0w + li) * 1024) + hh * 64 + gg * 16 + cc * 4] = v;
    }
}

// ---------------- launch ----------------------------------------------------------
extern "C" void kernel_launch(void* const* d_in, const int* in_sizes, int n_in,
                              void* d_out, int out_size, void* d_ws, size_t ws_size,
                              hipStream_t stream) {
    (void)in_sizes; (void)n_in; (void)out_size; (void)ws_size;
    const float* Hs = (const float*)d_in[0];
    const float* Wq = (const float*)d_in[1];
    const float* bq = (const float*)d_in[2];
    const float* Wk = (const float*)d_in[3];
    const float* bk = (const float*)d_in[4];
    // d_in[5], d_in[6] (Wv, bv) unused: reference's v uses the k projection.
    const float* Tt = (const float*)d_in[7];
    float* out = (float*)d_out;

    unsigned short* qbf   = (unsigned short*)d_ws;
    unsigned short* kbf   = qbf  + (size_t)8 * 1024 * 1024;
    unsigned short* kTbf  = kbf  + (size_t)8 * 1024 * 1024;
    unsigned short* Tbf   = kTbf + (size_t)8 * 1024 * 1024;
    unsigned short* Ahi   = Tbf  + (size_t)2048 * 64;
    unsigned short* Alo   = Ahi  + (size_t)8 * 1024 * 1024;
    unsigned short* WqThi = Alo  + (size_t)8 * 1024 * 1024;
    unsigned short* WqTlo = WqThi + (size_t)1024 * 1024;
    unsigned short* WkThi = WqTlo + (size_t)1024 * 1024;
    unsigned short* WkTlo = WkThi + (size_t)1024 * 1024;

    hipLaunchKernelGGL(prep_all, dim3(5120), dim3(256), 0, stream,
                       Tt, Tbf, Hs, Ahi, Alo, Wq, Wk, WqThi, WqTlo, WkThi, WkTlo);
    hipLaunchKernelGGL(proj_gemm, dim3(1024), dim3(256), 0, stream,
                       Ahi, Alo, WqThi, WqTlo, WkThi, WkTlo, bq, bk, qbf, kbf, kTbf);
    hipLaunchKernelGGL(attn, dim3(1024), dim3(512), 0, stream,
                       qbf, kbf, kTbf, Tbf, out);
}